// Round 1
// baseline (357.307 us; speedup 1.0000x reference)
//
#include <hip/hip_runtime.h>
#include <hip/hip_bf16.h>

#define NQ   14
#define DIM  16384      // 2^14
#define NPAIR 8192
#define BLK  1024
#define WMUL 0.6324555320336759f  // sqrt(2/5)

struct C2 { float x, y; };
__device__ inline C2 cmul(C2 a, C2 b){ return C2{a.x*b.x - a.y*b.y, a.x*b.y + a.y*b.x}; }
__device__ inline C2 cadd(C2 a, C2 b){ return C2{a.x+b.x, a.y+b.y}; }

// o = a*b (2x2 complex, row-major: [0]=00 [1]=01 [2]=10 [3]=11)
__device__ inline void mm2(const C2* a, const C2* b, C2* o) {
    o[0] = cadd(cmul(a[0],b[0]), cmul(a[1],b[2]));
    o[1] = cadd(cmul(a[0],b[1]), cmul(a[1],b[3]));
    o[2] = cadd(cmul(a[2],b[0]), cmul(a[3],b[2]));
    o[3] = cadd(cmul(a[2],b[1]), cmul(a[3],b[3]));
}

// rotation gate builders: type 0=rx, 1=ry, 2=rz
__device__ inline void build_gate(int ty, float t, C2* g) {
    float sn, cs;
    __sincosf(0.5f * t, &sn, &cs);
    if (ty == 0) {        // rx: [[c, -i s], [-i s, c]]
        g[0] = C2{cs, 0.f}; g[1] = C2{0.f, -sn};
        g[2] = C2{0.f, -sn}; g[3] = C2{cs, 0.f};
    } else if (ty == 1) { // ry: [[c, -s], [s, c]]
        g[0] = C2{cs, 0.f}; g[1] = C2{-sn, 0.f};
        g[2] = C2{sn, 0.f}; g[3] = C2{cs, 0.f};
    } else {              // rz: [[e^{-it/2}, 0], [0, e^{+it/2}]]
        g[0] = C2{cs, -sn}; g[1] = C2{0.f, 0.f};
        g[2] = C2{0.f, 0.f}; g[3] = C2{cs, sn};
    }
}

// gate-type sequence per layer (applied j=0,1,2 in order; fused M = g2*g1*g0)
__device__ const int TYPES[5][3] = {
    {0,1,2},  // XYZ
    {1,2,1},  // YZY
    {2,1,0},  // ZYX
    {0,2,0},  // XZX
    {1,2,1},  // YZY
};

__global__ __launch_bounds__(BLK) void qsim_kernel(
        const float* __restrict__ xr, const float* __restrict__ xi,
        const float* __restrict__ w, float* __restrict__ out) {
    __shared__ C2 s[DIM];          // 128 KiB statevector
    __shared__ C2 gm[5 * NQ * 4];  // 70 fused 2x2 complex gates
    __shared__ float red[BLK / 64];

    const int b   = blockIdx.x;
    const int tid = threadIdx.x;

    // ---- load state (coalesced) ----
    const float* xrb = xr + (size_t)b * DIM;
    const float* xib = xi + (size_t)b * DIM;
    for (int i = tid; i < DIM; i += BLK) s[i] = C2{xrb[i], xib[i]};

    // ---- build fused gate matrices (threads 0..69) ----
    if (tid < 5 * NQ) {
        const int li = tid / NQ, q = tid % NQ;
        C2 M[4], G[4], T[4];
        #pragma unroll
        for (int j = 0; j < 3; ++j) {
            float t = w[3 * NQ * li + 3 * q + j] * WMUL;
            build_gate(TYPES[li][j], t, G);
            if (j == 0) { M[0]=G[0]; M[1]=G[1]; M[2]=G[2]; M[3]=G[3]; }
            else {
                mm2(G, M, T);
                M[0]=T[0]; M[1]=T[1]; M[2]=T[2]; M[3]=T[3];
            }
        }
        #pragma unroll
        for (int k = 0; k < 4; ++k) gm[tid * 4 + k] = M[k];
    }
    __syncthreads();

    // ---- circuit ----
    for (int li = 0; li < 5; ++li) {
        // fused single-qubit rotations, qubit q -> bit (13-q)
        for (int q = 0; q < NQ; ++q) {
            const int bpos = 13 - q;
            const uint32_t lomask = (1u << bpos) - 1u;
            const C2 m00 = gm[(li*NQ+q)*4+0], m01 = gm[(li*NQ+q)*4+1];
            const C2 m10 = gm[(li*NQ+q)*4+2], m11 = gm[(li*NQ+q)*4+3];
            for (uint32_t p = tid; p < NPAIR; p += BLK) {
                uint32_t i0 = ((p & ~lomask) << 1) | (p & lomask);
                uint32_t i1 = i0 | (1u << bpos);
                C2 a0 = s[i0], a1 = s[i1];
                s[i0] = cadd(cmul(m00, a0), cmul(m01, a1));
                s[i1] = cadd(cmul(m10, a0), cmul(m11, a1));
            }
            __syncthreads();
        }
        // ring of CNOT (skip after last layer)
        if (li < 4) {
            for (int i = 0; i < NQ; ++i) {
                const int bc = 13 - i;
                const int bt = 13 - ((i + 1) % NQ);
                const int blo = bc < bt ? bc : bt;
                const int bhi = bc < bt ? bt : bc;
                const uint32_t lmask = (1u << blo) - 1u;
                const uint32_t mmask = (1u << (bhi - blo - 1)) - 1u;
                for (uint32_t p = tid; p < DIM / 4; p += BLK) {
                    // insert bits: control=1 at bc, target=0 at bt
                    uint32_t lo   = p & lmask;
                    uint32_t rest = p >> blo;
                    uint32_t mid  = rest & mmask;
                    uint32_t hi   = rest >> (bhi - blo - 1);
                    uint32_t idx  = lo | (mid << (blo + 1)) | (hi << (bhi + 1)) | (1u << bc);
                    uint32_t jdx  = idx | (1u << bt);
                    C2 t0 = s[idx]; s[idx] = s[jdx]; s[jdx] = t0;
                }
                __syncthreads();
            }
        }
    }

    // ---- <Z_0> : sign on bit 13 ----
    float local = 0.f;
    for (int i = tid; i < DIM; i += BLK) {
        C2 a = s[i];
        float m = a.x * a.x + a.y * a.y;
        local += (i & (1 << 13)) ? -m : m;
    }
    #pragma unroll
    for (int off = 32; off > 0; off >>= 1) local += __shfl_down(local, off);
    const int lane = tid & 63, wid = tid >> 6;
    if (lane == 0) red[wid] = local;
    __syncthreads();
    if (tid == 0) {
        float t = 0.f;
        #pragma unroll
        for (int k = 0; k < BLK / 64; ++k) t += red[k];
        out[b] = t;
    }
}

extern "C" void kernel_launch(void* const* d_in, const int* in_sizes, int n_in,
                              void* d_out, int out_size, void* d_ws, size_t ws_size,
                              hipStream_t stream) {
    const float* xr = (const float*)d_in[0];
    const float* xi = (const float*)d_in[1];
    const float* w  = (const float*)d_in[2];
    float* out = (float*)d_out;
    const int B = out_size;  // 512
    qsim_kernel<<<B, BLK, 0, stream>>>(xr, xi, w, out);
}